// Round 1
// baseline (522.257 us; speedup 1.0000x reference)
//
#include <hip/hip_runtime.h>
#include <stdint.h>

#define B_SZ   128
#define D_SZ   3072
#define N_SZ   20000
#define NPAD   20480   // padded N: 313*64 score tiles fit, 16 K-chunks * 1280 for drift

typedef __attribute__((ext_vector_type(8))) short  short8;
typedef __attribute__((ext_vector_type(4))) float  f32x4;

__device__ __forceinline__ unsigned short f2bf(float f) {
    unsigned u = __float_as_uint(f);
    u += 0x7FFFu + ((u >> 16) & 1u);   // round-to-nearest-even
    return (unsigned short)(u >> 16);
}
__device__ __forceinline__ float bf2f(unsigned short h) {
    return __uint_as_float(((unsigned)h) << 16);
}

__device__ __forceinline__ void gl_lds16(const void* g, void* l) {
    __builtin_amdgcn_global_load_lds(
        (const __attribute__((address_space(1))) void*)g,
        (__attribute__((address_space(3))) void*)l, 16, 0, 0);
}

// ---------------- Kernel A: split x into bf16 hi/lo ----------------
__global__ __launch_bounds__(256) void prep_x(const float* __restrict__ x,
                                              unsigned short* __restrict__ xhi,
                                              unsigned short* __restrict__ xlo)
{
    int i = blockIdx.x * 256 + threadIdx.x;     // exactly 128*3072
    float v = x[i];
    unsigned short h = f2bf(v);
    xhi[i] = h;
    xlo[i] = f2bf(v - bf2f(h));
}

// ---------------- Kernel B: scores S[b][n] = (tt*x.g - 0.5*tt^2*g2)/sig^2 ----
// block: 256 thr (4 waves), tile M=128 (all b) x N=64 gt rows, K-loop over 3072.
// split-precision: acc = xhi*ghi + xhi*glo + xlo*ghi  (fp32-accurate dot)
__global__ __launch_bounds__(256) void scores_kernel(
        const float* __restrict__ gt,
        const unsigned short* __restrict__ xhi,
        const unsigned short* __restrict__ xlo,
        const float* __restrict__ tarr,
        float* __restrict__ S)
{
    __shared__ __align__(16) unsigned short Xhi_t[128 * 32];
    __shared__ __align__(16) unsigned short Xlo_t[128 * 32];
    __shared__ __align__(16) unsigned short Ghi_t[64 * 32];
    __shared__ __align__(16) unsigned short Glo_t[64 * 32];
    __shared__ float c1buf[128];
    __shared__ float c2buf[128];
    __shared__ float g2buf[64];

    const int tid   = threadIdx.x;
    const int nbase = blockIdx.x * 64;

    if (tid < 128) {
        float tt  = tarr[tid] / 999.0f;
        float sig = 1.0f - tt;
        float inv = 1.0f / (sig * sig);
        c1buf[tid] = tt * inv;
        c2buf[tid] = 0.5f * tt * tt * inv;
    }

    const int lane = tid & 63;
    const int wave = tid >> 6;
    const int mh = wave & 1;      // M half (64 rows)
    const int nh = wave >> 1;     // N half (32 cols)
    const int lm = lane & 15;
    const int qd = lane >> 4;

    // G staging map: thread -> (row gn of 64, k-quarter gq of 4 -> 8 elems)
    const int gn = tid >> 2;
    const int gq = tid & 3;
    int grow = nbase + gn;
    if (grow > N_SZ - 1) grow = N_SZ - 1;   // clamp (scores for pad not stored)
    const float* gp0 = gt + (size_t)grow * D_SZ + gq * 8;

    float g2acc = 0.0f;

    f32x4 acc[4][2];
    #pragma unroll
    for (int i = 0; i < 4; i++)
        #pragma unroll
        for (int j = 0; j < 2; j++)
            acc[i][j] = (f32x4){0.f, 0.f, 0.f, 0.f};

    for (int k0 = 0; k0 < D_SZ; k0 += 32) {
        // stage X hi/lo via async global->LDS (lane-order contiguous)
        #pragma unroll
        for (int i = 0; i < 2; i++) {
            int o  = (i * 256 + tid) * 16;    // byte offset in 8KB tile
            int r  = o >> 6;                  // row (0..127)
            int ke = (o & 63) >> 1;           // elem in row (0,8,16,24)
            gl_lds16(xhi + (size_t)r * D_SZ + k0 + ke, (char*)Xhi_t + o);
            gl_lds16(xlo + (size_t)r * D_SZ + k0 + ke, (char*)Xlo_t + o);
        }
        // stage G: fp32 load, hi/lo bf16 split, fused g2 accumulation
        f32x4 v0 = *(const f32x4*)(gp0 + k0);
        f32x4 v1 = *(const f32x4*)(gp0 + k0 + 4);
        short8 h8, l8;
        #pragma unroll
        for (int j = 0; j < 4; j++) {
            float a = v0[j], b = v1[j];
            unsigned short ha = f2bf(a), hb = f2bf(b);
            h8[j]     = (short)ha;  h8[j + 4] = (short)hb;
            l8[j]     = (short)f2bf(a - bf2f(ha));
            l8[j + 4] = (short)f2bf(b - bf2f(hb));
            g2acc += a * a + b * b;
        }
        *(short8*)&Ghi_t[gn * 32 + gq * 8] = h8;
        *(short8*)&Glo_t[gn * 32 + gq * 8] = l8;

        __syncthreads();

        short8 bhi[2], blo[2];
        #pragma unroll
        for (int ni = 0; ni < 2; ni++) {
            int r = nh * 32 + ni * 16 + lm;
            bhi[ni] = *(short8*)&Ghi_t[r * 32 + qd * 8];
            blo[ni] = *(short8*)&Glo_t[r * 32 + qd * 8];
        }
        #pragma unroll
        for (int mi = 0; mi < 4; mi++) {
            int r = mh * 64 + mi * 16 + lm;
            short8 ahi = *(short8*)&Xhi_t[r * 32 + qd * 8];
            short8 alo = *(short8*)&Xlo_t[r * 32 + qd * 8];
            #pragma unroll
            for (int ni = 0; ni < 2; ni++) {
                acc[mi][ni] = __builtin_amdgcn_mfma_f32_16x16x32_bf16(ahi, bhi[ni], acc[mi][ni], 0, 0, 0);
                acc[mi][ni] = __builtin_amdgcn_mfma_f32_16x16x32_bf16(ahi, blo[ni], acc[mi][ni], 0, 0, 0);
                acc[mi][ni] = __builtin_amdgcn_mfma_f32_16x16x32_bf16(alo, bhi[ni], acc[mi][ni], 0, 0, 0);
            }
        }
        __syncthreads();
    }

    // reduce g2 over the 4 k-quarter threads of each row
    g2acc += __shfl_xor(g2acc, 1);
    g2acc += __shfl_xor(g2acc, 2);
    if (gq == 0) g2buf[gn] = g2acc;
    __syncthreads();

    // epilogue: C/D layout col=lane&15, row=qd*4+i  (m91-verified)
    #pragma unroll
    for (int mi = 0; mi < 4; mi++) {
        #pragma unroll
        for (int ni = 0; ni < 2; ni++) {
            int ncol = nh * 32 + ni * 16 + lm;
            int ng = nbase + ncol;
            if (ng < N_SZ) {
                float g2 = g2buf[ncol];
                #pragma unroll
                for (int i = 0; i < 4; i++) {
                    int m = mh * 64 + mi * 16 + qd * 4 + i;
                    S[(size_t)m * NPAD + ng] = c1buf[m] * acc[mi][ni][i] - c2buf[m] * g2;
                }
            }
        }
    }
}

// ---------------- Kernel C: per-row max, P = bf16(exp(s-m)), L = sum --------
__global__ __launch_bounds__(256) void softmax_stats(
        const float* __restrict__ S,
        unsigned short* __restrict__ P,
        float* __restrict__ L)
{
    const int b = blockIdx.x;
    const int tid = threadIdx.x;
    const int lane = tid & 63;
    const int wave = tid >> 6;
    const float* row = S + (size_t)b * NPAD;
    __shared__ float wred[4];

    float mx = -3.402823466e+38f;
    for (int n = tid; n < N_SZ; n += 256) mx = fmaxf(mx, row[n]);
    #pragma unroll
    for (int o = 32; o > 0; o >>= 1) mx = fmaxf(mx, __shfl_xor(mx, o));
    if (lane == 0) wred[wave] = mx;
    __syncthreads();
    mx = fmaxf(fmaxf(wred[0], wred[1]), fmaxf(wred[2], wred[3]));
    __syncthreads();

    float sum = 0.f;
    unsigned short* prow = P + (size_t)b * NPAD;
    for (int n = tid; n < NPAD; n += 256) {
        float p = 0.f;
        if (n < N_SZ) { p = expf(row[n] - mx); sum += p; }
        prow[n] = f2bf(p);            // pad region -> exact 0
    }
    #pragma unroll
    for (int o = 32; o > 0; o >>= 1) sum += __shfl_xor(sum, o);
    if (lane == 0) wred[wave] = sum;
    __syncthreads();
    if (tid == 0) L[b] = wred[0] + wred[1] + wred[2] + wred[3];
}

// ---------------- zero helper (Dacc) ----------------
__global__ __launch_bounds__(256) void zero_f32(float* __restrict__ p)
{
    p[blockIdx.x * 256 + threadIdx.x] = 0.f;   // exactly 128*3072
}

// ---------------- Kernel D: Dacc[b][d] += sum_k P[b][k]*gt_hi[k][d] ---------
// grid = 24 d-tiles * 16 K-chunks; tile M=128 x Nd=128, K-chunk 1280 (40 steps)
__global__ __launch_bounds__(256) void drift_kernel(
        const float* __restrict__ gt,
        const unsigned short* __restrict__ P,
        float* __restrict__ Dacc)
{
    __shared__ __align__(16) unsigned short Pt[128 * 32];
    __shared__ __align__(16) unsigned short Gt[128 * 40];  // [d][k], row 80B (64B data + 16B pad)

    const int tid = threadIdx.x;
    const int nt = blockIdx.x % 24;
    const int kc = blockIdx.x / 24;
    const int dbase = nt * 128;

    const int lane = tid & 63;
    const int wave = tid >> 6;
    const int mh = wave & 1;
    const int dh = wave >> 1;
    const int lm = lane & 15;
    const int qd = lane >> 4;

    // G staging map: thread -> (d-group of 4 cols, k-group of 4 rows)
    const int dg = tid & 31;
    const int kq = tid >> 5;

    f32x4 acc[4][4];
    #pragma unroll
    for (int i = 0; i < 4; i++)
        #pragma unroll
        for (int j = 0; j < 4; j++)
            acc[i][j] = (f32x4){0.f, 0.f, 0.f, 0.f};

    for (int s = 0; s < 40; s++) {
        int kb = kc * 1280 + s * 32;
        // stage P tile (128 x 32 bf16) direct to LDS; pad region of P is zero
        #pragma unroll
        for (int i = 0; i < 2; i++) {
            int o  = (i * 256 + tid) * 16;
            int r  = o >> 6;
            int ke = (o & 63) >> 1;
            gl_lds16(P + (size_t)r * NPAD + kb + ke, (char*)Pt + o);
        }
        // stage G transposed: global [k][d] fp32 -> LDS [d][k] bf16
        f32x4 row[4];
        #pragma unroll
        for (int i = 0; i < 4; i++) {
            int kg = kb + kq * 4 + i;
            if (kg > N_SZ - 1) kg = N_SZ - 1;   // clamp; P=0 there so product is 0
            row[i] = *(const f32x4*)(gt + (size_t)kg * D_SZ + dbase + dg * 4);
        }
        #pragma unroll
        for (int j = 0; j < 4; j++) {
            unsigned long long pk =
                  (unsigned long long)f2bf(row[0][j])
                | ((unsigned long long)f2bf(row[1][j]) << 16)
                | ((unsigned long long)f2bf(row[2][j]) << 32)
                | ((unsigned long long)f2bf(row[3][j]) << 48);
            *(unsigned long long*)((char*)Gt + (size_t)(dg * 4 + j) * 80 + kq * 8) = pk;
        }
        __syncthreads();

        short8 af[4], bf8[4];
        #pragma unroll
        for (int mi = 0; mi < 4; mi++)
            af[mi] = *(short8*)&Pt[(mh * 64 + mi * 16 + lm) * 32 + qd * 8];
        #pragma unroll
        for (int ni = 0; ni < 4; ni++)
            bf8[ni] = *(short8*)((char*)Gt + (size_t)(dh * 64 + ni * 16 + lm) * 80 + qd * 16);
        #pragma unroll
        for (int mi = 0; mi < 4; mi++)
            #pragma unroll
            for (int ni = 0; ni < 4; ni++)
                acc[mi][ni] = __builtin_amdgcn_mfma_f32_16x16x32_bf16(af[mi], bf8[ni], acc[mi][ni], 0, 0, 0);
        __syncthreads();
    }

    #pragma unroll
    for (int mi = 0; mi < 4; mi++)
        #pragma unroll
        for (int ni = 0; ni < 4; ni++) {
            int d = dbase + dh * 64 + ni * 16 + lm;
            #pragma unroll
            for (int i = 0; i < 4; i++) {
                int m = mh * 64 + mi * 16 + qd * 4 + i;
                atomicAdd(&Dacc[(size_t)m * D_SZ + d], acc[mi][ni][i]);
            }
        }
}

// ---------------- Kernel E: out = (Dacc/L - x)/sig ----------------
__global__ __launch_bounds__(256) void epilogue_kernel(
        const float* __restrict__ Dacc, const float* __restrict__ L,
        const float* __restrict__ x, const float* __restrict__ tarr,
        float* __restrict__ out)
{
    int i = blockIdx.x * 256 + threadIdx.x;   // exactly 128*3072
    int b = i / D_SZ;
    float tt = tarr[b] / 999.0f;
    float sig = 1.0f - tt;
    out[i] = (Dacc[i] / L[b] - x[i]) / sig;
}

extern "C" void kernel_launch(void* const* d_in, const int* in_sizes, int n_in,
                              void* d_out, int out_size, void* d_ws, size_t ws_size,
                              hipStream_t stream)
{
    const float* xt = (const float*)d_in[0];   // [128,3,32,32]
    const float* t  = (const float*)d_in[1];   // [128]
    const float* gt = (const float*)d_in[2];   // [20000,3,32,32]
    float* out = (float*)d_out;

    char* ws = (char*)d_ws;
    unsigned short* Xhi = (unsigned short*)(ws + 0);          //  786432 B
    unsigned short* Xlo = (unsigned short*)(ws + 786432);     //  786432 B
    float*          S   = (float*)         (ws + 1572864);    // 10485760 B  [128][20480]
    unsigned short* P   = (unsigned short*)(ws + 12058624);   //  5242880 B  [128][20480]
    float*          L   = (float*)         (ws + 17301504);   //      512 B
    float*          Dacc= (float*)         (ws + 17302528);   //  1572864 B
    // total ~18.9 MB

    prep_x        <<<1536, 256, 0, stream>>>(xt, Xhi, Xlo);
    scores_kernel <<< 313, 256, 0, stream>>>(gt, Xhi, Xlo, t, S);
    softmax_stats <<< 128, 256, 0, stream>>>(S, P, L);
    zero_f32      <<<1536, 256, 0, stream>>>(Dacc);
    drift_kernel  <<< 384, 256, 0, stream>>>(gt, P, Dacc);
    epilogue_kernel<<<1536, 256, 0, stream>>>(Dacc, L, xt, t, out);
}

// Round 2
// 494.134 us; speedup vs baseline: 1.0569x; 1.0569x over previous
//
#include <hip/hip_runtime.h>
#include <stdint.h>

#define B_SZ   128
#define D_SZ   3072
#define N_SZ   20000
#define NPAD   20480   // 313*64 score tiles (20032) < NPAD; 40 drift K-chunks * 512

typedef __attribute__((ext_vector_type(8))) short  short8;
typedef __attribute__((ext_vector_type(4))) float  f32x4;

__device__ __forceinline__ unsigned short f2bf(float f) {
    unsigned u = __float_as_uint(f);
    u += 0x7FFFu + ((u >> 16) & 1u);   // round-to-nearest-even
    return (unsigned short)(u >> 16);
}
__device__ __forceinline__ float bf2f(unsigned short h) {
    return __uint_as_float(((unsigned)h) << 16);
}
// order-preserving float<->uint key for atomicMax over signed floats
__device__ __forceinline__ unsigned fkey_enc(float f) {
    unsigned b = __float_as_uint(f);
    return (b & 0x80000000u) ? ~b : (b | 0x80000000u);
}
__device__ __forceinline__ float fkey_dec(unsigned u) {
    return __uint_as_float((u & 0x80000000u) ? (u ^ 0x80000000u) : ~u);
}

__device__ __forceinline__ void gl_lds16(const void* g, void* l) {
    __builtin_amdgcn_global_load_lds(
        (const __attribute__((address_space(1))) void*)g,
        (__attribute__((address_space(3))) void*)l, 16, 0, 0);
}

// ---------------- zero the accumulator region of ws ----------------
__global__ __launch_bounds__(256) void zero_ws(float* __restrict__ p)
{
    p[blockIdx.x * 256 + threadIdx.x] = 0.f;   // exact grid
}

// ---------------- split x into bf16 hi/lo ----------------
__global__ __launch_bounds__(256) void prep_x(const float* __restrict__ x,
                                              unsigned short* __restrict__ xhi,
                                              unsigned short* __restrict__ xlo)
{
    int i = blockIdx.x * 256 + threadIdx.x;     // exactly 128*3072
    float v = x[i];
    unsigned short h = f2bf(v);
    xhi[i] = h;
    xlo[i] = f2bf(v - bf2f(h));
}

// ---------------- scores: XG[b][n] += partial x.g ; G2[n] += partial g2 -----
// grid = 313 n-tiles * 8 K-chunks = 2504 blocks. Tile M=128 x N=64, K-chunk 384.
// split-precision: acc = xhi*ghi + xhi*glo + xlo*ghi  (fp32-accurate dot)
__global__ __launch_bounds__(256) void scores_kernel(
        const float* __restrict__ gt,
        const unsigned short* __restrict__ xhi,
        const unsigned short* __restrict__ xlo,
        float* __restrict__ XG,
        float* __restrict__ G2)
{
    __shared__ __align__(16) unsigned short Xhi_t[128 * 32];
    __shared__ __align__(16) unsigned short Xlo_t[128 * 32];
    __shared__ __align__(16) unsigned short Ghi_t[64 * 32];
    __shared__ __align__(16) unsigned short Glo_t[64 * 32];

    const int tid   = threadIdx.x;
    const int kc    = blockIdx.x & 7;        // K-chunk (8 x 384)
    const int nt    = blockIdx.x >> 3;       // n-tile (313)
    const int nbase = nt * 64;
    const int kcb   = kc * 384;

    const int lane = tid & 63;
    const int wave = tid >> 6;
    const int mh = wave & 1;      // M half (64 rows)
    const int nh = wave >> 1;     // N half (32 cols)
    const int lm = lane & 15;
    const int qd = lane >> 4;

    // G staging map: thread -> (row gn of 64, k-quarter gq of 4 -> 8 elems)
    const int gn = tid >> 2;
    const int gq = tid & 3;
    const int ng0 = nbase + gn;              // unclamped (for guards)
    int grow = ng0 > N_SZ - 1 ? N_SZ - 1 : ng0;
    const float* gp0 = gt + (size_t)grow * D_SZ + kcb + gq * 8;

    float g2acc = 0.0f;

    f32x4 acc[4][2];
    #pragma unroll
    for (int i = 0; i < 4; i++)
        #pragma unroll
        for (int j = 0; j < 2; j++)
            acc[i][j] = (f32x4){0.f, 0.f, 0.f, 0.f};

    for (int k0 = 0; k0 < 384; k0 += 32) {
        // stage X hi/lo via async global->LDS (lane-order contiguous)
        #pragma unroll
        for (int i = 0; i < 2; i++) {
            int o  = (i * 256 + tid) * 16;    // byte offset in 8KB tile
            int r  = o >> 6;                  // row (0..127)
            int ke = (o & 63) >> 1;           // elem in row (0,8,16,24)
            gl_lds16(xhi + (size_t)r * D_SZ + kcb + k0 + ke, (char*)Xhi_t + o);
            gl_lds16(xlo + (size_t)r * D_SZ + kcb + k0 + ke, (char*)Xlo_t + o);
        }
        // stage G: fp32 load, hi/lo bf16 split, fused g2 accumulation
        f32x4 v0 = *(const f32x4*)(gp0 + k0);
        f32x4 v1 = *(const f32x4*)(gp0 + k0 + 4);
        short8 h8, l8;
        #pragma unroll
        for (int j = 0; j < 4; j++) {
            float a = v0[j], b = v1[j];
            unsigned short ha = f2bf(a), hb = f2bf(b);
            h8[j]     = (short)ha;  h8[j + 4] = (short)hb;
            l8[j]     = (short)f2bf(a - bf2f(ha));
            l8[j + 4] = (short)f2bf(b - bf2f(hb));
            g2acc += a * a + b * b;
        }
        *(short8*)&Ghi_t[gn * 32 + gq * 8] = h8;
        *(short8*)&Glo_t[gn * 32 + gq * 8] = l8;

        __syncthreads();

        short8 bhi[2], blo[2];
        #pragma unroll
        for (int ni = 0; ni < 2; ni++) {
            int r = nh * 32 + ni * 16 + lm;
            bhi[ni] = *(short8*)&Ghi_t[r * 32 + qd * 8];
            blo[ni] = *(short8*)&Glo_t[r * 32 + qd * 8];
        }
        #pragma unroll
        for (int mi = 0; mi < 4; mi++) {
            int r = mh * 64 + mi * 16 + lm;
            short8 ahi = *(short8*)&Xhi_t[r * 32 + qd * 8];
            short8 alo = *(short8*)&Xlo_t[r * 32 + qd * 8];
            #pragma unroll
            for (int ni = 0; ni < 2; ni++) {
                acc[mi][ni] = __builtin_amdgcn_mfma_f32_16x16x32_bf16(ahi, bhi[ni], acc[mi][ni], 0, 0, 0);
                acc[mi][ni] = __builtin_amdgcn_mfma_f32_16x16x32_bf16(ahi, blo[ni], acc[mi][ni], 0, 0, 0);
                acc[mi][ni] = __builtin_amdgcn_mfma_f32_16x16x32_bf16(alo, bhi[ni], acc[mi][ni], 0, 0, 0);
            }
        }
        __syncthreads();
    }

    // g2 partial: reduce over the 4 k-quarter threads of each row, one atomic
    g2acc += __shfl_xor(g2acc, 1);
    g2acc += __shfl_xor(g2acc, 2);
    if (gq == 0 && ng0 < N_SZ) atomicAdd(&G2[ng0], g2acc);

    // epilogue: C/D layout col=lane&15, row=qd*4+i ; raw partial -> atomicAdd
    #pragma unroll
    for (int mi = 0; mi < 4; mi++) {
        #pragma unroll
        for (int ni = 0; ni < 2; ni++) {
            int ncol = nh * 32 + ni * 16 + lm;
            int ng = nbase + ncol;
            if (ng < N_SZ) {
                #pragma unroll
                for (int i = 0; i < 4; i++) {
                    int m = mh * 64 + mi * 16 + qd * 4 + i;
                    atomicAdd(&XG[(size_t)m * NPAD + ng], acc[mi][ni][i]);
                }
            }
        }
    }
}

// ---------------- maxk: row max of s = c1*xg - c2*g2, atomicMax per (b,chunk)
__global__ __launch_bounds__(256) void maxk(
        const float* __restrict__ XG, const float* __restrict__ G2,
        const float* __restrict__ tarr, unsigned* __restrict__ Mkey)
{
    const int b  = blockIdx.x >> 3;
    const int ch = blockIdx.x & 7;
    const int tid = threadIdx.x;
    float tt  = tarr[b] / 999.0f;
    float sig = 1.0f - tt;
    float inv = 1.0f / (sig * sig);
    float c1 = tt * inv, c2 = 0.5f * tt * tt * inv;
    const float* xg = XG + (size_t)b * NPAD;
    __shared__ float wred[4];

    float mx = -3.402823466e+38f;
    int n0 = ch * 2560;
    for (int n = n0 + tid; n < n0 + 2560; n += 256)
        if (n < N_SZ) mx = fmaxf(mx, c1 * xg[n] - c2 * G2[n]);
    #pragma unroll
    for (int o = 32; o > 0; o >>= 1) mx = fmaxf(mx, __shfl_xor(mx, o));
    if ((tid & 63) == 0) wred[tid >> 6] = mx;
    __syncthreads();
    if (tid == 0) {
        mx = fmaxf(fmaxf(wred[0], wred[1]), fmaxf(wred[2], wred[3]));
        atomicMax(&Mkey[b], fkey_enc(mx));
    }
}

// ---------------- expk: P = bf16(exp(s - m)), L[b] += partial sum ----------
__global__ __launch_bounds__(256) void expk(
        const float* __restrict__ XG, const float* __restrict__ G2,
        const float* __restrict__ tarr, const unsigned* __restrict__ Mkey,
        unsigned short* __restrict__ P, float* __restrict__ L)
{
    const int b  = blockIdx.x >> 3;
    const int ch = blockIdx.x & 7;
    const int tid = threadIdx.x;
    float tt  = tarr[b] / 999.0f;
    float sig = 1.0f - tt;
    float inv = 1.0f / (sig * sig);
    float c1 = tt * inv, c2 = 0.5f * tt * tt * inv;
    float m = fkey_dec(Mkey[b]);
    const float* xg = XG + (size_t)b * NPAD;
    unsigned short* prow = P + (size_t)b * NPAD;
    __shared__ float wred[4];

    float sum = 0.f;
    int n0 = ch * 2560;
    for (int n = n0 + tid; n < n0 + 2560; n += 256) {
        float p = 0.f;
        if (n < N_SZ) { p = expf(c1 * xg[n] - c2 * G2[n] - m); sum += p; }
        prow[n] = f2bf(p);            // pad region -> exact 0
    }
    #pragma unroll
    for (int o = 32; o > 0; o >>= 1) sum += __shfl_xor(sum, o);
    if ((tid & 63) == 0) wred[tid >> 6] = sum;
    __syncthreads();
    if (tid == 0) atomicAdd(&L[b], wred[0] + wred[1] + wred[2] + wred[3]);
}

// ---------------- drift: Dacc[b][d] += sum_k P[b][k]*gt_hi[k][d] -----------
// grid = 24 d-tiles * 40 K-chunks = 960 blocks; K-chunk 512 (16 steps of 32)
__global__ __launch_bounds__(256) void drift_kernel(
        const float* __restrict__ gt,
        const unsigned short* __restrict__ P,
        float* __restrict__ Dacc)
{
    __shared__ __align__(16) unsigned short Pt[128 * 32];
    __shared__ __align__(16) unsigned short Gt[128 * 40];  // [d][k], row 80B (64B data + 16B pad)

    const int tid = threadIdx.x;
    const int nt = blockIdx.x % 24;
    const int kc = blockIdx.x / 24;
    const int dbase = nt * 128;

    const int lane = tid & 63;
    const int wave = tid >> 6;
    const int mh = wave & 1;
    const int dh = wave >> 1;
    const int lm = lane & 15;
    const int qd = lane >> 4;

    // G staging map: thread -> (d-group of 4 cols, k-group of 4 rows)
    const int dg = tid & 31;
    const int kq = tid >> 5;

    f32x4 acc[4][4];
    #pragma unroll
    for (int i = 0; i < 4; i++)
        #pragma unroll
        for (int j = 0; j < 4; j++)
            acc[i][j] = (f32x4){0.f, 0.f, 0.f, 0.f};

    for (int s = 0; s < 16; s++) {
        int kb = kc * 512 + s * 32;
        // stage P tile (128 x 32 bf16) direct to LDS; pad region of P is zero
        #pragma unroll
        for (int i = 0; i < 2; i++) {
            int o  = (i * 256 + tid) * 16;
            int r  = o >> 6;
            int ke = (o & 63) >> 1;
            gl_lds16(P + (size_t)r * NPAD + kb + ke, (char*)Pt + o);
        }
        // stage G transposed: global [k][d] fp32 -> LDS [d][k] bf16
        f32x4 row[4];
        #pragma unroll
        for (int i = 0; i < 4; i++) {
            int kg = kb + kq * 4 + i;
            if (kg > N_SZ - 1) kg = N_SZ - 1;   // clamp; P=0 there so product is 0
            row[i] = *(const f32x4*)(gt + (size_t)kg * D_SZ + dbase + dg * 4);
        }
        #pragma unroll
        for (int j = 0; j < 4; j++) {
            unsigned long long pk =
                  (unsigned long long)f2bf(row[0][j])
                | ((unsigned long long)f2bf(row[1][j]) << 16)
                | ((unsigned long long)f2bf(row[2][j]) << 32)
                | ((unsigned long long)f2bf(row[3][j]) << 48);
            *(unsigned long long*)((char*)Gt + (size_t)(dg * 4 + j) * 80 + kq * 8) = pk;
        }
        __syncthreads();

        short8 af[4], bf8[4];
        #pragma unroll
        for (int mi = 0; mi < 4; mi++)
            af[mi] = *(short8*)&Pt[(mh * 64 + mi * 16 + lm) * 32 + qd * 8];
        #pragma unroll
        for (int ni = 0; ni < 4; ni++)
            bf8[ni] = *(short8*)((char*)Gt + (size_t)(dh * 64 + ni * 16 + lm) * 80 + qd * 16);
        #pragma unroll
        for (int mi = 0; mi < 4; mi++)
            #pragma unroll
            for (int ni = 0; ni < 4; ni++)
                acc[mi][ni] = __builtin_amdgcn_mfma_f32_16x16x32_bf16(af[mi], bf8[ni], acc[mi][ni], 0, 0, 0);
        __syncthreads();
    }

    #pragma unroll
    for (int mi = 0; mi < 4; mi++)
        #pragma unroll
        for (int ni = 0; ni < 4; ni++) {
            int d = dbase + dh * 64 + ni * 16 + lm;
            #pragma unroll
            for (int i = 0; i < 4; i++) {
                int m = mh * 64 + mi * 16 + qd * 4 + i;
                atomicAdd(&Dacc[(size_t)m * D_SZ + d], acc[mi][ni][i]);
            }
        }
}

// ---------------- epilogue: out = (Dacc/L - x)/sig ----------------
__global__ __launch_bounds__(256) void epilogue_kernel(
        const float* __restrict__ Dacc, const float* __restrict__ L,
        const float* __restrict__ x, const float* __restrict__ tarr,
        float* __restrict__ out)
{
    int i = blockIdx.x * 256 + threadIdx.x;   // exactly 128*3072
    int b = i / D_SZ;
    float tt = tarr[b] / 999.0f;
    float sig = 1.0f - tt;
    out[i] = (Dacc[i] / L[b] - x[i]) / sig;
}

extern "C" void kernel_launch(void* const* d_in, const int* in_sizes, int n_in,
                              void* d_out, int out_size, void* d_ws, size_t ws_size,
                              hipStream_t stream)
{
    const float* xt = (const float*)d_in[0];   // [128,3,32,32]
    const float* t  = (const float*)d_in[1];   // [128]
    const float* gt = (const float*)d_in[2];   // [20000,3,32,32]
    float* out = (float*)d_out;

    char* ws = (char*)d_ws;
    // zero-initialized accumulator region (contiguous, 12141568 B = 3035392 f32):
    float*          XG  = (float*)         (ws + 0);          // 10485760 B [128][20480]
    float*          G2  = (float*)         (ws + 10485760);   //    81920 B [20480]
    float*          Dacc= (float*)         (ws + 10567680);   //  1572864 B [128][3072]
    unsigned*       Mkey= (unsigned*)      (ws + 12140544);   //      512 B [128]
    float*          L   = (float*)         (ws + 12141056);   //      512 B [128]
    // non-zeroed scratch:
    unsigned short* Xhi = (unsigned short*)(ws + 12141568);   //   786432 B
    unsigned short* Xlo = (unsigned short*)(ws + 12928000);   //   786432 B
    unsigned short* P   = (unsigned short*)(ws + 13714432);   //  5242880 B [128][20480]
    // total ~19.0 MB

    zero_ws       <<<11857, 256, 0, stream>>>((float*)ws);       // 3035392 f32
    prep_x        <<< 1536, 256, 0, stream>>>(xt, Xhi, Xlo);
    scores_kernel <<< 2504, 256, 0, stream>>>(gt, Xhi, Xlo, XG, G2);
    maxk          <<< 1024, 256, 0, stream>>>(XG, G2, t, Mkey);
    expk          <<< 1024, 256, 0, stream>>>(XG, G2, t, Mkey, P, L);
    drift_kernel  <<<  960, 256, 0, stream>>>(gt, P, Dacc);
    epilogue_kernel<<<1536, 256, 0, stream>>>(Dacc, L, xt, t, out);
}